// Round 2
// baseline (1761.414 us; speedup 1.0000x reference)
//
#include <hip/hip_runtime.h>
#include <stdint.h>
#include <float.h>

#define K_DIM 2048
#define M_TOK 16384
#define N_EMB 16384

typedef __bf16 bf16x8 __attribute__((ext_vector_type(8)));
typedef float f32x4 __attribute__((ext_vector_type(4)));
typedef unsigned long long u64;

__device__ __forceinline__ ushort f2bf_rne(float f) {
  uint32_t u = __float_as_uint(f);
  u += 0x7FFFu + ((u >> 16) & 1u);
  return (ushort)(u >> 16);
}
// order-preserving float -> uint key (ascending float => ascending uint)
__device__ __forceinline__ uint32_t f2key(float f) {
  uint32_t u = __float_as_uint(f);
  return (u & 0x80000000u) ? ~u : (u | 0x80000000u);
}
__device__ __forceinline__ float key2f(uint32_t k) {
  uint32_t b = (k & 0x80000000u) ? (k & 0x7FFFFFFFu) : ~k;
  return __uint_as_float(b);
}
// ULP spacing of the binade containing v (v > 0)
__device__ __forceinline__ float ulpf(float v) {
  uint32_t e = __float_as_uint(v) & 0x7f800000u;
  return __uint_as_float(e) * 1.1920929e-7f;  // 2^-23 (exact pow2 mul)
}

// ---------------- fp32 -> bf16 (RNE) ----------------

__global__ void tobf16_kernel(const float* __restrict__ in, ushort* __restrict__ out) {
  long i = ((long)blockIdx.x * 256 + threadIdx.x) * 8;
  float4 a = *reinterpret_cast<const float4*>(in + i);
  float4 b = *reinterpret_cast<const float4*>(in + i + 4);
  ushort4 ha, hb;
  ha.x = f2bf_rne(a.x); ha.y = f2bf_rne(a.y); ha.z = f2bf_rne(a.z); ha.w = f2bf_rne(a.w);
  hb.x = f2bf_rne(b.x); hb.y = f2bf_rne(b.y); hb.z = f2bf_rne(b.z); hb.w = f2bf_rne(b.w);
  *reinterpret_cast<ushort4*>(out + i) = ha;
  *reinterpret_cast<ushort4*>(out + i + 4) = hb;
}

// ------- xx = np.sum(x*x, axis=1) replicating numpy AVX512 pairwise_sum -------
// 2048 = binary tree over 16 blocks of 128; each block: 8 zmm accumulators
// (one pass), combine ((r0+r1)+(r2+r3))+((r4+r5)+(r6+r7)) per lane, then
// _mm512_reduce_add_ps lane tree. All ops fp32 RNE, no FMA contraction.

__global__ void xx_kernel(const float* __restrict__ x, float* __restrict__ xxArr) {
#pragma clang fp contract(off)
  int row = blockIdx.x * 16 + (threadIdx.x >> 4);
  int blk = threadIdx.x & 15;
  const float* p = x + (long)row * K_DIM + blk * 128;
  float S[16];
#pragma unroll
  for (int L = 0; L < 16; ++L) {
    float p0 = p[L] * p[L];
    float p1 = p[L + 16] * p[L + 16];
    float p2 = p[L + 32] * p[L + 32];
    float p3 = p[L + 48] * p[L + 48];
    float p4 = p[L + 64] * p[L + 64];
    float p5 = p[L + 80] * p[L + 80];
    float p6 = p[L + 96] * p[L + 96];
    float p7 = p[L + 112] * p[L + 112];
    S[L] = ((p0 + p1) + (p2 + p3)) + ((p4 + p5) + (p6 + p7));
  }
  // _mm512_reduce_add_ps tree
  float T1[8], T3[4];
#pragma unroll
  for (int L = 0; L < 8; ++L) T1[L] = S[L] + S[L + 8];
#pragma unroll
  for (int L = 0; L < 4; ++L) T3[L] = T1[L] + T1[L + 4];
  float blksum = (T3[0] + T3[2]) + (T3[1] + T3[3]);
  __shared__ float lds[16][16];
  lds[threadIdx.x >> 4][blk] = blksum;
  __syncthreads();
  if (blk == 0) {
    const float* b = lds[threadIdx.x >> 4];
    float r1[8], r2[4];
#pragma unroll
    for (int i = 0; i < 8; ++i) r1[i] = b[2 * i] + b[2 * i + 1];
#pragma unroll
    for (int i = 0; i < 4; ++i) r2[i] = r1[2 * i] + r1[2 * i + 1];
    xxArr[row] = (r2[0] + r2[1]) + (r2[2] + r2[3]);
  }
}

// ---------------- bf16 GEMM + per-stripe top-2 coarse argmin ----------------
// 256x256 tile, BK=32, 8 waves (2m x 4n), per-wave 128x64. Coarse score
// s = -2*dot_bf16 (error ~2e-6 << margin). Packed entry: key18<<14 | idx14.

#define GLOAD_LDS16(g, s)                                              \
  __builtin_amdgcn_global_load_lds(                                    \
      (const __attribute__((address_space(1))) void*)(g),              \
      (__attribute__((address_space(3))) void*)(s), 16, 0, 0)

__global__ __launch_bounds__(512, 2) void gemm_argmin_kernel(
    const ushort* __restrict__ xh, const ushort* __restrict__ eh,
    u64* __restrict__ stripes) {
  __shared__ __attribute__((aligned(16))) ushort sX[256 * 32];
  __shared__ __attribute__((aligned(16))) ushort sE[256 * 32];

  int b = blockIdx.x;
  int wg = (b & 7) * 512 + (b >> 3);  // XCD-aware swizzle (4096 % 8 == 0)
  int bx = wg & 63, by = wg >> 6;
  long m0 = (long)by * 256, n0 = (long)bx * 256;

  int t = threadIdx.x;
  int lane = t & 63, wid = t >> 6;
  int wm = wid >> 2, wn = wid & 3;

  int r4 = t >> 2;
  int c8 = (t & 3) * 8;
  long ga0 = (m0 + r4) * K_DIM + c8;
  long ga1 = (m0 + 128 + r4) * K_DIM + c8;
  long gb0 = (n0 + r4) * K_DIM + c8;
  long gb1 = (n0 + 128 + r4) * K_DIM + c8;

  f32x4 acc[8][4] = {};
  int arow = lane & 15;
  int kg8 = (lane >> 4) * 8;

  for (int kb = 0; kb < K_DIM; kb += 32) {
    GLOAD_LDS16(xh + ga0 + kb, sX + t * 8);
    GLOAD_LDS16(xh + ga1 + kb, sX + 4096 + t * 8);
    GLOAD_LDS16(eh + gb0 + kb, sE + t * 8);
    GLOAD_LDS16(eh + gb1 + kb, sE + 4096 + t * 8);
    __syncthreads();

    bf16x8 ah[8], bh[4];
#pragma unroll
    for (int i = 0; i < 8; ++i)
      ah[i] = *reinterpret_cast<const bf16x8*>(&sX[(wm * 128 + i * 16 + arow) * 32 + kg8]);
#pragma unroll
    for (int j = 0; j < 4; ++j)
      bh[j] = *reinterpret_cast<const bf16x8*>(&sE[(wn * 64 + j * 16 + arow) * 32 + kg8]);
#pragma unroll
    for (int i = 0; i < 8; ++i)
#pragma unroll
      for (int j = 0; j < 4; ++j)
        acc[i][j] = __builtin_amdgcn_mfma_f32_16x16x32_bf16(ah[i], bh[j], acc[i][j], 0, 0, 0);
    __syncthreads();
  }

  // epilogue: per-row top-2 over this wave's 64 columns
  int stripe = (int)(n0 >> 6) + wn;  // 0..255
#pragma unroll
  for (int i = 0; i < 8; ++i) {
#pragma unroll
    for (int r = 0; r < 4; ++r) {
      uint32_t p1 = 0xFFFFFFFFu, p2 = 0xFFFFFFFFu;
#pragma unroll
      for (int j = 0; j < 4; ++j) {
        float sv = -2.0f * acc[i][j][r];
        uint32_t n = (uint32_t)(n0 + wn * 64 + j * 16 + arow);
        uint32_t pk = ((f2key(sv) >> 14) << 14) | n;
        if (pk < p1) { p2 = p1; p1 = pk; }
        else if (pk < p2) { p2 = pk; }
      }
#pragma unroll
      for (int ms = 1; ms < 16; ms <<= 1) {
        uint32_t q1 = __shfl_xor(p1, ms, 64);
        uint32_t q2 = __shfl_xor(p2, ms, 64);
        uint32_t m1 = min(p1, q1);
        uint32_t m2 = min(max(p1, q1), min(p2, q2));
        p1 = m1; p2 = m2;
      }
      if ((lane & 15) == 0) {
        long gm = m0 + wm * 128 + i * 16 + (lane >> 4) * 4 + r;
        stripes[gm * 256 + stripe] = ((u64)p1 << 32) | p2;
      }
    }
  }
}

// ---- resolve: emulate np fp32 d = fl(xx - 2*fl(dot)), argmin, tie->lowest n ----

__global__ void resolve_kernel(const u64* __restrict__ stripes,
                               const float* __restrict__ x,
                               const float* __restrict__ emb,
                               const float* __restrict__ xxArr,
                               float* __restrict__ outIdxF,
                               int* __restrict__ idxOut) {
#pragma clang fp contract(off)
  int w = threadIdx.x >> 6;
  int row = blockIdx.x * 4 + w;
  int lane = threadIdx.x & 63;
  const u64* sp = stripes + (long)row * 256;

  uint32_t mine[8];
  uint32_t pmin = 0xFFFFFFFFu;
#pragma unroll
  for (int q = 0; q < 4; ++q) {
    u64 v = sp[lane + q * 64];
    mine[2 * q] = (uint32_t)(v >> 32);
    mine[2 * q + 1] = (uint32_t)v;
    pmin = min(pmin, mine[2 * q]);  // p1 <= p2
  }
#pragma unroll
  for (int ms = 1; ms < 64; ms <<= 1) pmin = min(pmin, __shfl_xor(pmin, ms, 64));

  float xxf = xxArr[row];
  // margin: one fp32 grid cell of d (~xx) + slack for bf16 coarse error + key quant
  float smin_lb = key2f((pmin >> 14) << 14);
  float thr = smin_lb + ulpf(fabsf(xxf) + 0.03f) + 1e-4f;
  uint32_t kthr = f2key(thr) >> 14;

  int cnt = 0;
#pragma unroll
  for (int q = 0; q < 8; ++q) cnt += ((mine[q] >> 14) <= kthr) ? 1 : 0;
#pragma unroll
  for (int ms = 1; ms < 64; ms <<= 1) cnt += __shfl_xor(cnt, ms, 64);

  __shared__ int cand[4][32];
  __shared__ int ccount[4];
  bool need = (cnt > 1);
  if (lane == 0) ccount[w] = 0;
  __syncthreads();
  if (need) {
#pragma unroll
    for (int q = 0; q < 8; ++q) {
      if ((mine[q] >> 14) <= kthr) {
        int slot = atomicAdd(&ccount[w], 1);
        if (slot < 32) cand[w][slot] = (int)(mine[q] & 0x3FFFu);
      }
    }
  }
  __syncthreads();

  int winner;
  if (!need) {
    winner = (int)(pmin & 0x3FFFu);
  } else {
    int nc = min(ccount[w], 32);
    float bestd = FLT_MAX;
    int bestn = 0x7fffffff;
    const float* xr = x + (long)row * K_DIM;
    for (int c = 0; c < nc; ++c) {
      int n = cand[w][c];
      const float* er = emb + (long)n * K_DIM;
      double ds = 0.0;
      for (int k = lane; k < K_DIM; k += 64)
        ds += (double)xr[k] * (double)er[k];
#pragma unroll
      for (int ms = 1; ms < 64; ms <<= 1) ds += __shfl_xor(ds, ms, 64);
      float dotf = (float)ds;        // fl32(dot) — np's einsum output grid
      float t2 = 2.0f * dotf;        // exact x2
      float dq = xxf - t2;           // fp32 RNE: fl(xx - t2) == np's d (t1 == xx)
      if (dq < bestd || (dq == bestd && n < bestn)) { bestd = dq; bestn = n; }
    }
    winner = bestn;
  }
  if (lane == 0) { outIdxF[row] = (float)winner; idxOut[row] = winner; }
}

// ---------------- gather z_q = embedding[idx] ----------------

__global__ void gather_kernel(const float* __restrict__ emb,
                              const int* __restrict__ idx,
                              float* __restrict__ zq) {
  int row = blockIdx.x, t = threadIdx.x;
  long n = idx[row];
  const float4* s = reinterpret_cast<const float4*>(emb + n * K_DIM);
  float4* d = reinterpret_cast<float4*>(zq + (long)row * K_DIM);
  d[t] = s[t];
  d[t + 256] = s[t + 256];
}

// ---------------- launch ----------------

extern "C" void kernel_launch(void* const* d_in, const int* in_sizes, int n_in,
                              void* d_out, int out_size, void* d_ws, size_t ws_size,
                              hipStream_t stream) {
  const float* x = (const float*)d_in[0];
  const float* emb = (const float*)d_in[1];
  float* out = (float*)d_out;

  // workspace layout (~96.2 MiB)
  char* ws = (char*)d_ws;
  ushort* xh = (ushort*)ws;                               // 64 MiB
  u64* stripes = (u64*)(ws + 67108864);                   // 32 MiB
  float* xxArr = (float*)(ws + 100663296);                // 64 KiB
  int* idxbuf = (int*)(ws + 100728832);                   // 64 KiB

  // e in bf16 overlaid in z_q output region (overwritten by gather at the end)
  ushort* ehh = (ushort*)d_out;                           // 64 MiB

  tobf16_kernel<<<16384, 256, 0, stream>>>(x, xh);
  tobf16_kernel<<<16384, 256, 0, stream>>>(emb, ehh);
  xx_kernel<<<1024, 256, 0, stream>>>(x, xxArr);
  gemm_argmin_kernel<<<4096, 512, 0, stream>>>(xh, ehh, stripes);
  resolve_kernel<<<4096, 256, 0, stream>>>(stripes, x, emb, xxArr, out + 33554432, idxbuf);
  gather_kernel<<<16384, 256, 0, stream>>>(emb, idxbuf, out);
}

// Round 3
// 1390.070 us; speedup vs baseline: 1.2671x; 1.2671x over previous
//
#include <hip/hip_runtime.h>
#include <stdint.h>
#include <float.h>

#define K_DIM 2048
#define M_TOK 16384
#define N_EMB 16384
#define NKT 32  // K-tiles of 64

typedef __bf16 bf16x8 __attribute__((ext_vector_type(8)));
typedef float f32x4 __attribute__((ext_vector_type(4)));
typedef unsigned long long u64;

__device__ __forceinline__ ushort f2bf_rne(float f) {
  uint32_t u = __float_as_uint(f);
  u += 0x7FFFu + ((u >> 16) & 1u);
  return (ushort)(u >> 16);
}
__device__ __forceinline__ uint32_t f2key(float f) {
  uint32_t u = __float_as_uint(f);
  return (u & 0x80000000u) ? ~u : (u | 0x80000000u);
}
__device__ __forceinline__ float key2f(uint32_t k) {
  uint32_t b = (k & 0x80000000u) ? (k & 0x7FFFFFFFu) : ~k;
  return __uint_as_float(b);
}
__device__ __forceinline__ float ulpf(float v) {
  uint32_t e = __float_as_uint(v) & 0x7f800000u;
  return __uint_as_float(e) * 1.1920929e-7f;  // 2^-23
}

// ---------------- fp32 -> bf16 (RNE) ----------------

__global__ void tobf16_kernel(const float* __restrict__ in, ushort* __restrict__ out) {
  long i = ((long)blockIdx.x * 256 + threadIdx.x) * 8;
  float4 a = *reinterpret_cast<const float4*>(in + i);
  float4 b = *reinterpret_cast<const float4*>(in + i + 4);
  ushort4 ha, hb;
  ha.x = f2bf_rne(a.x); ha.y = f2bf_rne(a.y); ha.z = f2bf_rne(a.z); ha.w = f2bf_rne(a.w);
  hb.x = f2bf_rne(b.x); hb.y = f2bf_rne(b.y); hb.z = f2bf_rne(b.z); hb.w = f2bf_rne(b.w);
  *reinterpret_cast<ushort4*>(out + i) = ha;
  *reinterpret_cast<ushort4*>(out + i + 4) = hb;
}

// ------- xx = np.sum(x*x, axis=1) replicating numpy AVX512 pairwise_sum -------

__global__ void xx_kernel(const float* __restrict__ x, float* __restrict__ xxArr) {
#pragma clang fp contract(off)
  int row = blockIdx.x * 16 + (threadIdx.x >> 4);
  int blk = threadIdx.x & 15;
  const float* p = x + (long)row * K_DIM + blk * 128;
  float S[16];
#pragma unroll
  for (int L = 0; L < 16; ++L) {
    float p0 = p[L] * p[L];
    float p1 = p[L + 16] * p[L + 16];
    float p2 = p[L + 32] * p[L + 32];
    float p3 = p[L + 48] * p[L + 48];
    float p4 = p[L + 64] * p[L + 64];
    float p5 = p[L + 80] * p[L + 80];
    float p6 = p[L + 96] * p[L + 96];
    float p7 = p[L + 112] * p[L + 112];
    S[L] = ((p0 + p1) + (p2 + p3)) + ((p4 + p5) + (p6 + p7));
  }
  float T1[8], T3[4];
#pragma unroll
  for (int L = 0; L < 8; ++L) T1[L] = S[L] + S[L + 8];
#pragma unroll
  for (int L = 0; L < 4; ++L) T3[L] = T1[L] + T1[L + 4];
  float blksum = (T3[0] + T3[2]) + (T3[1] + T3[3]);
  __shared__ float lds[16][16];
  lds[threadIdx.x >> 4][blk] = blksum;
  __syncthreads();
  if (blk == 0) {
    const float* b = lds[threadIdx.x >> 4];
    float r1[8], r2[4];
#pragma unroll
    for (int i = 0; i < 8; ++i) r1[i] = b[2 * i] + b[2 * i + 1];
#pragma unroll
    for (int i = 0; i < 4; ++i) r2[i] = r1[2 * i] + r1[2 * i + 1];
    xxArr[row] = (r2[0] + r2[1]) + (r2[2] + r2[3]);
  }
}

// ---------------- bf16 GEMM + per-stripe top-2 coarse argmin ----------------
// 256x256 tile, BK=64, 8 waves (2m x 4n), per-wave 128x64 out (8x4 frags).
// LDS: 2 K-tile buffers x {A 256x64, B 256x64} bf16 = 128 KiB, XOR-swizzled
// (elem col ^ ((row&7)<<3)) via pre-swizzled global source (rule #21).
// Pipeline: 2-deep counted vmcnt(8): STAGE(kt+2) issued right after the
// barrier freeing buf[kt&1]; kt+1's 8 loads verified landed, kt+2's fly.

#define GLOAD_LDS16(g, s)                                              \
  __builtin_amdgcn_global_load_lds(                                    \
      (const __attribute__((address_space(1))) void*)(g),              \
      (__attribute__((address_space(3))) void*)(s), 16, 0, 0)

__global__ __launch_bounds__(512, 2) void gemm_argmin_kernel(
    const ushort* __restrict__ xh, const ushort* __restrict__ eh,
    u64* __restrict__ stripes) {
  __shared__ __attribute__((aligned(16))) ushort lds[65536];  // 128 KiB

  int b = blockIdx.x;
  int wg = (b & 7) * 512 + (b >> 3);  // XCD-aware swizzle (4096 % 8 == 0)
  int bx = wg & 63, by = wg >> 6;
  int m0 = by * 256, n0 = bx * 256;

  int t = threadIdx.x;
  int lane = t & 63, wid = t >> 6;
  int wm = wid >> 2, wn = wid & 3;
  int arow = lane & 15;
  int kg8 = (lane >> 4) * 8;

  // staging: thread t, gload g in 0..3 per operand covers row g*64+(t>>3),
  // 16B chunk (t&7); global col pre-swizzled so linear LDS + swizzled read match.
  int srow = t >> 3;
  int swz8 = (((t & 7) ^ (srow & 7)) << 3);
  const ushort* gA = xh + (unsigned)(m0 + srow) * 2048u + swz8;
  const ushort* gB = eh + (unsigned)(n0 + srow) * 2048u + swz8;

#define STAGE(KT, BS)                                                  \
  {                                                                    \
    const ushort* _ga = gA + (KT) * 64;                                \
    const ushort* _gb = gB + (KT) * 64;                                \
    ushort* _l = (ushort*)lds + (BS) * 32768 + t * 8;                  \
    _Pragma("unroll") for (int g = 0; g < 4; ++g) {                    \
      GLOAD_LDS16(_ga + g * 131072, _l + g * 4096);                    \
      GLOAD_LDS16(_gb + g * 131072, _l + 16384 + g * 4096);            \
    }                                                                  \
  }

  f32x4 acc[8][4] = {};
  int xr = (arow & 7) << 3;               // row-XOR term (rows used are 16-aligned + arow)
  int ck0 = kg8 ^ xr;                     // swizzled col offset, k-step 0
  int ck1 = (32 + kg8) ^ xr;              // k-step 1

  STAGE(0, 0);
  STAGE(1, 1);
  asm volatile("s_waitcnt vmcnt(8)" ::: "memory");  // K-tile 0 landed
  __builtin_amdgcn_s_barrier();

  for (int kt = 0; kt < NKT; ++kt) {
    const ushort* Ab = (const ushort*)lds + (kt & 1) * 32768;
    const ushort* Bb = Ab + 16384;

    bf16x8 bfr[4][2];
#pragma unroll
    for (int j = 0; j < 4; ++j) {
      int rb = (wn * 64 + j * 16 + arow) * 64;
      bfr[j][0] = *reinterpret_cast<const bf16x8*>(Bb + rb + ck0);
      bfr[j][1] = *reinterpret_cast<const bf16x8*>(Bb + rb + ck1);
    }
#pragma unroll
    for (int ih = 0; ih < 2; ++ih) {
      bf16x8 afr[4][2];
#pragma unroll
      for (int i4 = 0; i4 < 4; ++i4) {
        int ra = (wm * 128 + (ih * 4 + i4) * 16 + arow) * 64;
        afr[i4][0] = *reinterpret_cast<const bf16x8*>(Ab + ra + ck0);
        afr[i4][1] = *reinterpret_cast<const bf16x8*>(Ab + ra + ck1);
      }
      __builtin_amdgcn_s_setprio(1);
#pragma unroll
      for (int i4 = 0; i4 < 4; ++i4)
#pragma unroll
        for (int j = 0; j < 4; ++j) {
          acc[ih * 4 + i4][j] = __builtin_amdgcn_mfma_f32_16x16x32_bf16(
              afr[i4][0], bfr[j][0], acc[ih * 4 + i4][j], 0, 0, 0);
          acc[ih * 4 + i4][j] = __builtin_amdgcn_mfma_f32_16x16x32_bf16(
              afr[i4][1], bfr[j][1], acc[ih * 4 + i4][j], 0, 0, 0);
        }
      __builtin_amdgcn_s_setprio(0);
    }
    __builtin_amdgcn_s_barrier();  // all waves done reading buf[kt&1]
    if (kt <= NKT - 3) {
      STAGE(kt + 2, kt & 1);       // refill just-freed buffer
      asm volatile("s_waitcnt vmcnt(8)" ::: "memory");  // kt+1 landed; kt+2 in flight
    } else {
      asm volatile("s_waitcnt vmcnt(0)" ::: "memory");  // tail drain (kt=30: kt+1=31)
    }
    __builtin_amdgcn_s_barrier();  // publish
  }

  // epilogue: per-row top-2 over this wave's 64 columns; score = -2*dot
  int stripe = (bx << 2) + wn;  // 0..255
#pragma unroll
  for (int i = 0; i < 8; ++i) {
#pragma unroll
    for (int r = 0; r < 4; ++r) {
      uint32_t p1 = 0xFFFFFFFFu, p2 = 0xFFFFFFFFu;
#pragma unroll
      for (int j = 0; j < 4; ++j) {
        float sv = -2.0f * acc[i][j][r];
        uint32_t n = (uint32_t)(n0 + wn * 64 + j * 16 + arow);
        uint32_t pk = ((f2key(sv) >> 14) << 14) | n;
        if (pk < p1) { p2 = p1; p1 = pk; }
        else if (pk < p2) { p2 = pk; }
      }
#pragma unroll
      for (int ms = 1; ms < 16; ms <<= 1) {
        uint32_t q1 = __shfl_xor(p1, ms, 64);
        uint32_t q2 = __shfl_xor(p2, ms, 64);
        uint32_t m1 = min(p1, q1);
        uint32_t m2 = min(max(p1, q1), min(p2, q2));
        p1 = m1; p2 = m2;
      }
      if ((lane & 15) == 0) {
        long gm = m0 + wm * 128 + i * 16 + (lane >> 4) * 4 + r;
        stripes[gm * 256 + stripe] = ((u64)p1 << 32) | p2;
      }
    }
  }
#undef STAGE
}

// ---- resolve: emulate np fp32 d = fl(xx - 2*fl(dot)), argmin, tie->lowest n ----

__global__ void resolve_kernel(const u64* __restrict__ stripes,
                               const float* __restrict__ x,
                               const float* __restrict__ emb,
                               const float* __restrict__ xxArr,
                               float* __restrict__ outIdxF,
                               int* __restrict__ idxOut) {
#pragma clang fp contract(off)
  int w = threadIdx.x >> 6;
  int row = blockIdx.x * 4 + w;
  int lane = threadIdx.x & 63;
  const u64* sp = stripes + (long)row * 256;

  uint32_t mine[8];
  uint32_t pmin = 0xFFFFFFFFu;
#pragma unroll
  for (int q = 0; q < 4; ++q) {
    u64 v = sp[lane + q * 64];
    mine[2 * q] = (uint32_t)(v >> 32);
    mine[2 * q + 1] = (uint32_t)v;
    pmin = min(pmin, mine[2 * q]);
  }
#pragma unroll
  for (int ms = 1; ms < 64; ms <<= 1) pmin = min(pmin, __shfl_xor(pmin, ms, 64));

  float xxf = xxArr[row];
  float smin_lb = key2f((pmin >> 14) << 14);
  float thr = smin_lb + ulpf(fabsf(xxf) + 0.03f) + 1e-4f;
  uint32_t kthr = f2key(thr) >> 14;

  int cnt = 0;
#pragma unroll
  for (int q = 0; q < 8; ++q) cnt += ((mine[q] >> 14) <= kthr) ? 1 : 0;
#pragma unroll
  for (int ms = 1; ms < 64; ms <<= 1) cnt += __shfl_xor(cnt, ms, 64);

  __shared__ int cand[4][32];
  __shared__ int ccount[4];
  bool need = (cnt > 1);
  if (lane == 0) ccount[w] = 0;
  __syncthreads();
  if (need) {
#pragma unroll
    for (int q = 0; q < 8; ++q) {
      if ((mine[q] >> 14) <= kthr) {
        int slot = atomicAdd(&ccount[w], 1);
        if (slot < 32) cand[w][slot] = (int)(mine[q] & 0x3FFFu);
      }
    }
  }
  __syncthreads();

  int winner;
  if (!need) {
    winner = (int)(pmin & 0x3FFFu);
  } else {
    int nc = min(ccount[w], 32);
    float bestd = FLT_MAX;
    int bestn = 0x7fffffff;
    const float* xr = x + (long)row * K_DIM;
    for (int c = 0; c < nc; ++c) {
      int n = cand[w][c];
      const float* er = emb + (long)n * K_DIM;
      double ds = 0.0;
      for (int k = lane; k < K_DIM; k += 64)
        ds += (double)xr[k] * (double)er[k];
#pragma unroll
      for (int ms = 1; ms < 64; ms <<= 1) ds += __shfl_xor(ds, ms, 64);
      float dotf = (float)ds;
      float t2 = 2.0f * dotf;
      float dq = xxf - t2;
      if (dq < bestd || (dq == bestd && n < bestn)) { bestd = dq; bestn = n; }
    }
    winner = bestn;
  }
  if (lane == 0) { outIdxF[row] = (float)winner; idxOut[row] = winner; }
}

// ---------------- gather z_q = embedding[idx] ----------------

__global__ void gather_kernel(const float* __restrict__ emb,
                              const int* __restrict__ idx,
                              float* __restrict__ zq) {
  int row = blockIdx.x, t = threadIdx.x;
  long n = idx[row];
  const float4* s = reinterpret_cast<const float4*>(emb + n * K_DIM);
  float4* d = reinterpret_cast<float4*>(zq + (long)row * K_DIM);
  d[t] = s[t];
  d[t + 256] = s[t + 256];
}

// ---------------- launch ----------------

extern "C" void kernel_launch(void* const* d_in, const int* in_sizes, int n_in,
                              void* d_out, int out_size, void* d_ws, size_t ws_size,
                              hipStream_t stream) {
  const float* x = (const float*)d_in[0];
  const float* emb = (const float*)d_in[1];
  float* out = (float*)d_out;

  char* ws = (char*)d_ws;
  ushort* xh = (ushort*)ws;                               // 64 MiB
  u64* stripes = (u64*)(ws + 67108864);                   // 32 MiB
  float* xxArr = (float*)(ws + 100663296);                // 64 KiB
  int* idxbuf = (int*)(ws + 100728832);                   // 64 KiB

  ushort* ehh = (ushort*)d_out;                           // 64 MiB (overlay, gather overwrites)

  tobf16_kernel<<<16384, 256, 0, stream>>>(x, xh);
  tobf16_kernel<<<16384, 256, 0, stream>>>(emb, ehh);
  xx_kernel<<<1024, 256, 0, stream>>>(x, xxArr);
  gemm_argmin_kernel<<<4096, 512, 0, stream>>>(xh, ehh, stripes);
  resolve_kernel<<<4096, 256, 0, stream>>>(stripes, x, emb, xxArr, out + 33554432, idxbuf);
  gather_kernel<<<16384, 256, 0, stream>>>(emb, idxbuf, out);
}